// Round 1
// baseline (249.698 us; speedup 1.0000x reference)
//
#include <hip/hip_runtime.h>
#include <math.h>

// NT=64, NR=4, DK=2, KU=8, BR=16, BATCH=256
// channel:    [B][64][4][16][16] f32 (last dim: 8 re, 8 im)
// prediction: [B][2560] = U[4][2][16][16] ++ W[2][2][16][8]
// out:        [B][64][2][8][2] f32
//
// R9 = R8 (95us dispatch) restructured for 1024 threads / 16 waves per CU:
//  - quad phase: 4 f-quarters x 256 threads (butterfly layout unchanged),
//    4 fi iters each; T/H LDS tiles gain a [grp] dim (133 KB)
//  - partial merge: pair-tree (g0/g2 write AugA/AugB -> g1/g3 RMW ->
//    combine straight into GJ registers; old Aug write-back pass deleted)
//  - Gauss-Jordan: 16 threads/row x 5 cols (was 8 x 10) -> critical-path
//    wave does half the dependent work per pivot iteration
// Rationale: VALUBusy 50%, Occupancy 21% -> latency-bound at 2 waves/SIMD;
// 4 waves/SIMD fills stall slots without changing total VALU work.

#define SAUG 84   // float2 stride of Aug rows
#define STP  65   // float4 stride of paired TtP/HtP rows

namespace {
union alignas(16) ShU {
    struct { float4 TtP[2][4][8][STP]; float4 HtP[2][4][8][STP]; } p1; // 133120 B
    struct { float2 A[64][SAUG]; float2 B[64][SAUG]; } aug;            // 86016 B
};
union alignas(16) ShV {
    struct { float2 U[4 * 258]; float W[512]; } in;                    // 10304 B
    float2 xout[64][17];                                               // 8704 B
};
}

__device__ __forceinline__ float2 cmul(float2 x, float2 y) {
    return make_float2(x.x * y.x - x.y * y.y, x.x * y.y + x.y * y.x);
}

__global__ __launch_bounds__(1024)
void uw2v_kernel(const float* __restrict__ channel,
                 const float* __restrict__ prediction,
                 float2* __restrict__ out)
{
    __shared__ ShU sh;
    __shared__ ShV sv;
    __shared__ alignas(16) float2 prow[2][80];   // pivot-row double buffer
    __shared__ float2 redbuf[16];
    __shared__ float  fred[16];

    const int b   = blockIdx.x;
    const int tid = threadIdx.x;
    const int wv  = tid >> 6;
    const float* pred = prediction + (size_t)b * 2560;
    const float* chan = channel + (size_t)b * 65536;

    // ---- load U (re/im merged, padded per-r stride) and W ----
    {
        int m = tid;                                 // [r][d][f][k], 1024 entries
        int r = m >> 8, d = (m >> 7) & 1, f = (m >> 3) & 15, k = m & 7;
        const float* src = pred + (((r * 2 + d) * 16 + f) << 4);
        sv.in.U[r * 258 + ((d * 16 + f) << 3) + k] = make_float2(src[k], src[k + 8]);
    }
    if (tid < 512) sv.in.W[tid] = pred[2048 + tid];
    __syncthreads();

    const int grp = tid >> 8;                        // f-quarter 0..3
    const int lt  = tid & 255;
    const int t4 = lt >> 2, r4 = lt & 3;
    const int a  = lt >> 4, bb = lt & 15;
    const int bit0 = r4 & 1, bit1 = (r4 >> 1) & 1;
    const int kkb  = 4 * bit0 + 2 * bit1;            // owned k-slice base (even)
    const int mpb  = kkb >> 1;                       // owned m-pair row (0..3)
    const int fbase = grp << 2;
    const int tr_r = lt >> 5, tr_d = (lt >> 4) & 1, tr_e = (lt >> 3) & 1, tr_k = lt & 7;

    // split accumulators: accA = sum t_re*h, accB = sum t_im*h (h = (re,im))
    float2 accA[4][4], accB[4][4];
    #pragma unroll
    for (int i = 0; i < 4; ++i)
        #pragma unroll
        for (int j = 0; j < 4; ++j) {
            accA[i][j] = make_float2(0.f, 0.f);
            accB[i][j] = make_float2(0.f, 0.f);
        }
    float2 huw[4] = {make_float2(0,0), make_float2(0,0), make_float2(0,0), make_float2(0,0)};
    float2 tracc  = make_float2(0.f, 0.f);

    const float* hbase = chan + ((t4 * 4 + r4) << 8) + (fbase << 4);

    #pragma unroll 1
    for (int fi = 0; fi < 4; ++fi) {
        const int f = fbase + fi;
        const float4 ca = *(const float4*)(hbase + (fi << 4) + 0);
        const float4 cb = *(const float4*)(hbase + (fi << 4) + 4);
        const float4 ci = *(const float4*)(hbase + (fi << 4) + 8);
        const float4 cd = *(const float4*)(hbase + (fi << 4) + 12);

        const float4* U0p = (const float4*)&sv.in.U[r4 * 258 + (f << 3)];        // d=0
        const float4* U1p = (const float4*)&sv.in.U[r4 * 258 + ((16 + f) << 3)]; // d=1
        const float4 u0q0 = U0p[0], u0q1 = U0p[1], u0q2 = U0p[2], u0q3 = U0p[3];
        const float4 u1q0 = U1p[0], u1q1 = U1p[1], u1q2 = U1p[2], u1q3 = U1p[3];

        // partials: val0[k] = conj(H)*U (d=0, m=k), val1[k] (d=1, m=8+k)
        float2 val0[8], val1[8];
        #define MK2(K, HR, HI, U0R, U0I, U1R, U1I) \
            val0[K] = make_float2((HR)*(U0R) + (HI)*(U0I), (HR)*(U0I) - (HI)*(U0R)); \
            val1[K] = make_float2((HR)*(U1R) + (HI)*(U1I), (HR)*(U1I) - (HI)*(U1R));
        MK2(0, ca.x, ci.x, u0q0.x, u0q0.y, u1q0.x, u1q0.y)
        MK2(1, ca.y, ci.y, u0q0.z, u0q0.w, u1q0.z, u1q0.w)
        MK2(2, ca.z, ci.z, u0q1.x, u0q1.y, u1q1.x, u1q1.y)
        MK2(3, ca.w, ci.w, u0q1.z, u0q1.w, u1q1.z, u1q1.w)
        MK2(4, cb.x, cd.x, u0q2.x, u0q2.y, u1q2.x, u1q2.y)
        MK2(5, cb.y, cd.y, u0q2.z, u0q2.w, u1q2.z, u1q2.w)
        MK2(6, cb.z, cd.z, u0q3.x, u0q3.y, u1q3.x, u1q3.y)
        MK2(7, cb.w, cd.w, u0q3.z, u0q3.w, u1q3.z, u1q3.w)
        #undef MK2

        // stage 1 (xor 1): keep k in {4*bit0 .. 4*bit0+3}
        float2 s1d0[4], s1d1[4];
        #pragma unroll
        for (int q = 0; q < 4; ++q) {
            float2 k0 = bit0 ? val0[4 + q] : val0[q];
            float2 n0 = bit0 ? val0[q]     : val0[4 + q];
            float2 k1 = bit0 ? val1[4 + q] : val1[q];
            float2 n1 = bit0 ? val1[q]     : val1[4 + q];
            n0.x = __shfl_xor(n0.x, 1); n0.y = __shfl_xor(n0.y, 1);
            n1.x = __shfl_xor(n1.x, 1); n1.y = __shfl_xor(n1.y, 1);
            s1d0[q] = make_float2(k0.x + n0.x, k0.y + n0.y);
            s1d1[q] = make_float2(k1.x + n1.x, k1.y + n1.y);
        }
        // stage 2 (xor 2): keep q in {2*bit1, 2*bit1+1} -> hh[kkb+jj]
        float2 h0[2], h1[2];
        #pragma unroll
        for (int jj = 0; jj < 2; ++jj) {
            float2 k0 = bit1 ? s1d0[2 + jj] : s1d0[jj];
            float2 n0 = bit1 ? s1d0[jj]     : s1d0[2 + jj];
            float2 k1 = bit1 ? s1d1[2 + jj] : s1d1[jj];
            float2 n1 = bit1 ? s1d1[jj]     : s1d1[2 + jj];
            n0.x = __shfl_xor(n0.x, 2); n0.y = __shfl_xor(n0.y, 2);
            n1.x = __shfl_xor(n1.x, 2); n1.y = __shfl_xor(n1.y, 2);
            h0[jj] = make_float2(k0.x + n0.x, k0.y + n0.y);
            h1[jj] = make_float2(k1.x + n1.x, k1.y + n1.y);
        }

        // tr_UWU partial (128 lanes per group; wave-uniform branch)
        if (lt < 128) {
            float w   = sv.in.W[((tr_d * 2 + tr_e) * 16 + f) * 8 + tr_k];
            float2 u1 = sv.in.U[tr_r * 258 + ((tr_d * 16 + f) << 3) + tr_k];
            float2 u2 = sv.in.U[tr_r * 258 + ((tr_e * 16 + f) << 3) + tr_k];
            tracc.x += w * (u1.x * u2.x + u1.y * u2.y);
            tracc.y += w * (u1.y * u2.x - u1.x * u2.y);
        }

        // T pairs + H pairs (b128 writes, m-pair rows)
        const int p = fi & 1;
        #pragma unroll
        for (int e = 0; e < 2; ++e) {
            float w0a = sv.in.W[(e * 16 + f) * 8 + kkb];
            float w0b = sv.in.W[(e * 16 + f) * 8 + kkb + 1];
            float w1a = sv.in.W[((2 + e) * 16 + f) * 8 + kkb];
            float w1b = sv.in.W[((2 + e) * 16 + f) * 8 + kkb + 1];
            float2 tva = make_float2(h0[0].x * w0a + h1[0].x * w1a,
                                     h0[0].y * w0a + h1[0].y * w1a);
            float2 tvb = make_float2(h0[1].x * w0b + h1[1].x * w1b,
                                     h0[1].y * w0b + h1[1].y * w1b);
            sh.p1.TtP[p][grp][e * 4 + mpb][t4] = make_float4(tva.x, tva.y, tvb.x, tvb.y);
            huw[e * 2 + 0].x += tva.x; huw[e * 2 + 0].y += tva.y;
            huw[e * 2 + 1].x += tvb.x; huw[e * 2 + 1].y += tvb.y;
        }
        sh.p1.HtP[p][grp][mpb][t4]     = make_float4(h0[0].x, h0[0].y, h0[1].x, h0[1].y);
        sh.p1.HtP[p][grp][4 + mpb][t4] = make_float4(h1[0].x, h1[0].y, h1[1].x, h1[1].y);
        __syncthreads();

        // quad: accA/accB [i][j] over m-pairs (b128 reads, broadcast-friendly)
        #pragma unroll
        for (int mp = 0; mp < 8; ++mp) {
            float4 tq[4], hq[4];
            #pragma unroll
            for (int i = 0; i < 4; ++i) tq[i] = sh.p1.TtP[p][grp][mp][a + 16 * i];
            #pragma unroll
            for (int j = 0; j < 4; ++j) hq[j] = sh.p1.HtP[p][grp][mp][bb + 16 * j];
            #pragma unroll
            for (int i = 0; i < 4; ++i)
                #pragma unroll
                for (int j = 0; j < 4; ++j) {
                    float2 va = accA[i][j], vb = accB[i][j];
                    va.x = fmaf(tq[i].x, hq[j].x, va.x);
                    va.y = fmaf(tq[i].x, hq[j].y, va.y);
                    vb.x = fmaf(tq[i].y, hq[j].x, vb.x);
                    vb.y = fmaf(tq[i].y, hq[j].y, vb.y);
                    va.x = fmaf(tq[i].z, hq[j].z, va.x);
                    va.y = fmaf(tq[i].z, hq[j].w, va.y);
                    vb.x = fmaf(tq[i].w, hq[j].z, vb.x);
                    vb.y = fmaf(tq[i].w, hq[j].w, vb.y);
                    accA[i][j] = va; accB[i][j] = vb;
                }
        }
    }

    // ---- tr_UWU block reduction (barrier also retires last TtP reads) ----
    #pragma unroll
    for (int off = 32; off; off >>= 1) {
        tracc.x += __shfl_xor(tracc.x, off);
        tracc.y += __shfl_xor(tracc.y, off);
    }
    if ((tid & 63) == 0) redbuf[wv] = tracc;
    __syncthreads();
    float2 trv = make_float2(0.f, 0.f);
    #pragma unroll
    for (int w = 0; w < 16; ++w) { trv.x += redbuf[w].x; trv.y += redbuf[w].y; }
    trv.x *= 0.1f; trv.y *= 0.1f;

    // ---- pair-tree merge of the 4 f-quarter partials ----
    // qacc = (accA.x + accB.y, accB.x - accA.y)
    if ((grp & 1) == 0) {                            // g0 -> AugA, g2 -> AugB
        float2 (*Dst)[SAUG] = (grp == 0) ? sh.aug.A : sh.aug.B;
        #pragma unroll
        for (int i = 0; i < 4; ++i)
            #pragma unroll
            for (int j = 0; j < 4; ++j) {
                Dst[a + 16 * i][bb + 16 * j] =
                    make_float2(accA[i][j].x + accB[i][j].y,
                                accB[i][j].x - accA[i][j].y);
            }
        #pragma unroll
        for (int e = 0; e < 2; ++e)
            #pragma unroll
            for (int jj = 0; jj < 2; ++jj)
                Dst[t4][64 + e * 8 + kkb + jj] = huw[e * 2 + jj];
    }
    __syncthreads();
    if (grp & 1) {                                   // g1 RMW AugA, g3 RMW AugB
        float2 (*Dst)[SAUG] = (grp == 1) ? sh.aug.A : sh.aug.B;
        #pragma unroll
        for (int i = 0; i < 4; ++i)
            #pragma unroll
            for (int j = 0; j < 4; ++j) {
                float2 v = Dst[a + 16 * i][bb + 16 * j];
                v.x += accA[i][j].x + accB[i][j].y;
                v.y += accB[i][j].x - accA[i][j].y;
                Dst[a + 16 * i][bb + 16 * j] = v;
            }
        #pragma unroll
        for (int e = 0; e < 2; ++e)
            #pragma unroll
            for (int jj = 0; jj < 2; ++jj) {
                int col = 64 + e * 8 + kkb + jj;
                float2 v = Dst[t4][col];
                v.x += huw[e * 2 + jj].x; v.y += huw[e * 2 + jj].y;
                Dst[t4][col] = v;
            }
    }
    __syncthreads();

    // ---- combine A+B (+trv on diag) straight into GJ registers ----
    const int gi = tid >> 4, gc = tid & 15;          // 64 rows x 16 col-slices
    const int cb = gc * 5;                           // 5 cols per thread
    const int lanebase = (tid & 63) & 48;

    float2 xr[5];
    #pragma unroll
    for (int c = 0; c < 5; ++c) {
        float2 v = sh.aug.A[gi][cb + c];
        float2 w = sh.aug.B[gi][cb + c];
        v.x += w.x; v.y += w.y;
        if (gi == cb + c) { v.x += trv.x; v.y += trv.y; }
        xr[c] = v;
    }
    if (gi == 0) {
        #pragma unroll
        for (int c = 0; c < 5; ++c) prow[0][cb + c] = xr[c];
    }
    __syncthreads();

    // ---- Gauss-Jordan: register-resident rows, diagonal pivots ----
    float2 myipv = make_float2(0.f, 0.f);

    #pragma unroll 1
    for (int ks = 0; ks < 64; ++ks) {
        const int pb = ks & 1;
        float2 pr[5];
        #pragma unroll
        for (int c = 0; c < 5; ++c) pr[c] = prow[pb][cb + c];

        float2 z = prow[pb][ks];
        float  zi = 1.0f / (z.x * z.x + z.y * z.y);
        float2 ipv = make_float2(z.x * zi, -z.y * zi);

        float2 cand = make_float2(0.f, 0.f);
        #pragma unroll
        for (int c = 0; c < 5; ++c)
            if (cb + c == ks) cand = xr[c];
        int srcl = lanebase + (ks / 5);
        float2 Lv;
        Lv.x = __shfl(cand.x, srcl);
        Lv.y = __shfl(cand.y, srcl);

        if (gi == ks) {
            myipv = ipv;
        } else {
            float2 L = cmul(Lv, ipv);
            #pragma unroll
            for (int c = 0; c < 5; ++c) {
                xr[c].x -= L.x * pr[c].x - L.y * pr[c].y;
                xr[c].y -= L.x * pr[c].y + L.y * pr[c].x;
            }
        }
        if (gi == ks + 1) {
            #pragma unroll
            for (int c = 0; c < 5; ++c) prow[pb ^ 1][cb + c] = xr[c];
        }
        __syncthreads();
    }

    // ---- extract solution (cols 64..79), normalize, write ----
    float ss = 0.f;
    if (gc >= 12) {
        #pragma unroll
        for (int c = 0; c < 5; ++c) {
            int col = cb + c;
            if (col >= 64) {
                float2 xv = cmul(xr[c], myipv);
                ss += xv.x * xv.x + xv.y * xv.y;
                sv.xout[gi][col - 64] = xv;
            }
        }
    }
    #pragma unroll
    for (int off = 32; off; off >>= 1) ss += __shfl_xor(ss, off);
    if ((tid & 63) == 0) fred[wv] = ss;
    __syncthreads();
    float total = 0.f;
    #pragma unroll
    for (int w = 0; w < 16; ++w) total += fred[w];
    float invn = rsqrtf(total);
    {
        float2 v = sv.xout[tid >> 4][tid & 15];
        out[(size_t)b * 1024 + tid] = make_float2(v.x * invn, v.y * invn);
    }
}

extern "C" void kernel_launch(void* const* d_in, const int* in_sizes, int n_in,
                              void* d_out, int out_size, void* d_ws, size_t ws_size,
                              hipStream_t stream) {
    const float* channel    = (const float*)d_in[0];
    const float* prediction = (const float*)d_in[1];
    int batch = in_sizes[0] / 65536;   // 256
    uw2v_kernel<<<dim3(batch), dim3(1024), 0, stream>>>(channel, prediction,
                                                        (float2*)d_out);
}